// Round 1
// 470.974 us; speedup vs baseline: 1.2492x; 1.2492x over previous
//
#include <hip/hip_runtime.h>

// Problem constants
#define NTOK 343   // tokens per window (7*7*7)
#define NPAD 352   // 22 * 16
#define CEMB 192
#define NH   6
#define HD   32
#define NB   256
#define NWIN 64

typedef __attribute__((ext_vector_type(8))) short short8;   // 8 x bf16 bits
typedef __attribute__((ext_vector_type(4))) float f32x4;

__device__ __forceinline__ unsigned short f2bf(float f) {
    unsigned int u = __builtin_bit_cast(unsigned int, f);
    u += 0x7fffu + ((u >> 16) & 1u);          // round-to-nearest-even
    return (unsigned short)(u >> 16);
}
__device__ __forceinline__ float bf2f(unsigned short h) {
    unsigned int u = ((unsigned int)h) << 16;
    return __builtin_bit_cast(float, u);
}
__device__ __forceinline__ short8 pack8(float4 f0, float4 f1) {
    short8 r;
    r[0] = (short)f2bf(f0.x); r[1] = (short)f2bf(f0.y);
    r[2] = (short)f2bf(f0.z); r[3] = (short)f2bf(f0.w);
    r[4] = (short)f2bf(f1.x); r[5] = (short)f2bf(f1.y);
    r[6] = (short)f2bf(f1.z); r[7] = (short)f2bf(f1.w);
    return r;
}

// ---------------- prep: weights -> bf16 (scale folded into qw) ----------------
__global__ void prep_weights(const float* __restrict__ qw, const float* __restrict__ kvw,
                             const float* __restrict__ pw,
                             unsigned short* __restrict__ qwb, unsigned short* __restrict__ kvwb,
                             unsigned short* __restrict__ pwb) {
    const float scale = 0.17677669529663689f;   // 32^-0.5 folded into Q weights
    int idx = blockIdx.x * 256 + threadIdx.x;
    if (idx < 36864)        qwb[idx] = f2bf(qw[idx] * scale);
    else if (idx < 110592)  kvwb[idx - 36864] = f2bf(kvw[idx - 36864]);
    else if (idx < 147456)  pwb[idx - 110592] = f2bf(pw[idx - 110592]);
}

// ---------------- prep: biasT[h][key][q] (bf16, padded to 352x352) ----------------
__global__ void prep_biasT(const float* __restrict__ table, const int* __restrict__ rel,
                           unsigned short* __restrict__ biasT) {
    __shared__ int sidx[32 * 33];
    int bid = blockIdx.x;                  // 121 blocks: kt*11 + qt
    int kt = bid / 11, qt = bid - kt * 11;
    int k0 = kt * 32, q0 = qt * 32;
    for (int e = threadIdx.x; e < 1024; e += 256) {
        int i = e >> 5, j = e & 31;        // i: q-local, j: key-local
        int q = q0 + i, k = k0 + j;
        sidx[i * 33 + j] = (q < NTOK && k < NTOK) ? rel[q * NTOK + k] : -1;
    }
    __syncthreads();
    for (int h = 0; h < NH; h++) {
        for (int e = threadIdx.x; e < 1024; e += 256) {
            int kk = e >> 5, qq = e & 31;
            int idx = sidx[qq * 33 + kk];
            float v = (idx >= 0) ? table[idx * NH + h] : 0.f;
            biasT[((size_t)h * NPAD + (k0 + kk)) * NPAD + (q0 + qq)] = f2bf(v);
        }
    }
}

// ---------------- prep: maskT[w][key][q] (bf16, padded) ----------------
__global__ void prep_maskT(const float* __restrict__ mask, unsigned short* __restrict__ maskT) {
    __shared__ float sm[32 * 33];
    int bid = blockIdx.x;                  // 64*121 blocks
    int w = bid / 121;
    int rem = bid - w * 121;
    int kt = rem / 11, qt = rem - kt * 11;
    int k0 = kt * 32, q0 = qt * 32;
    for (int e = threadIdx.x; e < 1024; e += 256) {
        int i = e >> 5, j = e & 31;        // i: q-local, j: key-local
        int q = q0 + i, k = k0 + j;
        sm[i * 33 + j] = (q < NTOK && k < NTOK) ? mask[((size_t)w * NTOK + q) * NTOK + k] : 0.f;
    }
    __syncthreads();
    for (int e = threadIdx.x; e < 1024; e += 256) {
        int kk = e >> 5, qq = e & 31;
        maskT[((size_t)w * NPAD + (k0 + kk)) * NPAD + (q0 + qq)] = f2bf(sm[qq * 33 + kk]);
    }
}

// ---------------- QKV projection GEMM ----------------
// One block per (b, o) with o in {Q, K, V}. Weights staged once into padded LDS
// ([192][200] shorts, 76.8 KB -> 2 blocks/CU); B-frags via ds_read_b128
// (row step = 100 dwords == 4 banks mod 32 -> worst 2-way alias, free).
// A from global fp32 (full 128B-line consumption), acc in regs.
// Outputs: Qb[b][352][192] (scaled via weights), Kb[b][352][192],
//          Vtb[b][h][d 32][m 360] (transposed for PV B-frags).
__global__ __launch_bounds__(512, 2)
void qkv_kernel(const float* __restrict__ x_in, const float* __restrict__ x_cross,
                const unsigned short* __restrict__ qwb, const unsigned short* __restrict__ kvwb,
                unsigned short* __restrict__ Qb, unsigned short* __restrict__ Kb,
                unsigned short* __restrict__ Vtb) {
    extern __shared__ char smem[];
    unsigned short* Ws = (unsigned short*)smem;      // [192][200] padded
    const int tid = threadIdx.x;
    const int wave = tid >> 6, lane = tid & 63;
    const int quad = lane >> 4, l16 = lane & 15;
    const int b = blockIdx.x / 3, o = blockIdx.x % 3;
    const float* xsrc = (o == 0) ? x_in : x_cross;
    const unsigned short* wsrc = (o == 0) ? qwb : (o == 1 ? kvwb : (kvwb + 192 * CEMB));
    const f32x4 zero4 = {0.f, 0.f, 0.f, 0.f};

    // stage this output's 192x192 bf16 weight matrix into LDS (coalesced 16B chunks)
    for (int i = tid; i < 4608; i += 512) {
        int r = i / 24, c8 = i - r * 24;
        *(short8*)(Ws + r * 200 + c8 * 8) = *(const short8*)(wsrc + (size_t)r * CEMB + c8 * 8);
    }
    __syncthreads();

    for (int mi = 0; mi < 3; mi++) {
        int mt = wave + (mi << 3);
        if (mt >= 22) continue;            // wave-uniform
        int row = mt * 16 + l16;
        f32x4 acc[12];
#pragma unroll
        for (int nt = 0; nt < 12; nt++) acc[nt] = zero4;
#pragma unroll
        for (int kc = 0; kc < 6; kc++) {
            short8 a = {};
            if (row < NTOK) {
                const float* xp = xsrc + ((size_t)b * NTOK + row) * CEMB + kc * 32 + (quad << 3);
                float4 f0 = *(const float4*)xp;
                float4 f1 = *(const float4*)(xp + 4);
                a = pack8(f0, f1);
            }
#pragma unroll
            for (int nt = 0; nt < 12; nt++) {
                const short8 bf = *(const short8*)(Ws + (nt * 16 + l16) * 200 + kc * 32 + (quad << 3));
                acc[nt] = __builtin_amdgcn_mfma_f32_16x16x32_bf16(a, bf, acc[nt], 0, 0, 0);
            }
        }
        if (o < 2) {
            unsigned short* dst = (o == 0 ? Qb : Kb) + (size_t)b * NPAD * CEMB;
#pragma unroll
            for (int nt = 0; nt < 12; nt++) {
#pragma unroll
                for (int r = 0; r < 4; r++) {
                    int m = mt * 16 + (quad << 2) + r;
                    dst[(size_t)m * CEMB + nt * 16 + l16] = f2bf(acc[nt][r]);
                }
            }
        } else {
#pragma unroll
            for (int nt = 0; nt < 12; nt++) {
                int h = nt >> 1, d = ((nt & 1) << 4) + l16;
#pragma unroll
                for (int r = 0; r < 4; r++) {
                    int m = mt * 16 + (quad << 2) + r;
                    Vtb[(((size_t)b * NH + h) * 32 + d) * 360 + m] = f2bf(acc[nt][r]);
                }
            }
        }
    }
}

// ---------------- fused attention per (window b, head h) ----------------
// LDS (dynamic, 63488 B): Ks[352][40] @0 (28160), Vt[32][360] @28160 (23040),
// P strips 8 x [16][48] @51200 (12288). 2 blocks/CU.
// Streaming PV: per 32-key chunk, 2 S-MFMAs -> exp -> P strip -> 2 PV MFMAs.
__global__ __launch_bounds__(512, 4)
void attn_kernel(const unsigned short* __restrict__ Qb, const unsigned short* __restrict__ Kb,
                 const unsigned short* __restrict__ Vtb,
                 const unsigned short* __restrict__ biasT, const unsigned short* __restrict__ maskT,
                 unsigned short* __restrict__ attnb) {
    extern __shared__ char smem[];
    unsigned short* Ks = (unsigned short*)smem;             // [352][40]
    unsigned short* Vt = (unsigned short*)(smem + 28160);   // [32][360]
    unsigned short* Pb = (unsigned short*)(smem + 51200);   // 8 x [16][48]

    const int tid = threadIdx.x;
    const int wave = tid >> 6, lane = tid & 63;
    const int quad = lane >> 4, l16 = lane & 15;
    const int b = blockIdx.x / NH, h = blockIdx.x - (blockIdx.x / NH) * NH;
    const f32x4 zero4 = {0.f, 0.f, 0.f, 0.f};

    // stage K (this head's 32 channels) into B-frag layout [key][40]
    for (int i = tid; i < 1408; i += 512) {
        int key = i >> 2, part = i & 3;
        *(short8*)(Ks + key * 40 + part * 8) =
            *(const short8*)(Kb + ((size_t)b * NPAD + key) * CEMB + h * 32 + part * 8);
    }
    // stage V^T (contiguous copy of this (b,h) plane)
    const unsigned short* vsrc = Vtb + (size_t)(b * NH + h) * 32 * 360;
    for (int i = tid; i < 1440; i += 512) {
        *(short8*)(Vt + i * 8) = *(const short8*)(vsrc + i * 8);
    }
    // per-wave Q A-frags straight from global
    short8 qa[3] = {};
#pragma unroll
    for (int i = 0; i < 3; i++) {
        int mt = wave + (i << 3);
        if (mt < 22)
            qa[i] = *(const short8*)(Qb + ((size_t)b * NPAD + mt * 16 + l16) * CEMB + h * 32 + (quad << 3));
    }
    __syncthreads();

    unsigned short* P = Pb + wave * 768;    // [16][48]
    const unsigned short* biasTp = biasT + (size_t)h * NPAD * NPAD;
    const unsigned short* maskTp = maskT + (size_t)(b & 63) * NPAD * NPAD;
#pragma unroll
    for (int i = 0; i < 3; i++) {
        int mt = wave + (i << 3);
        if (mt >= 22) continue;             // wave-uniform, no barriers below
        const int q0 = mt * 16 + (quad << 2);
        float rp[4] = {0.f, 0.f, 0.f, 0.f};
        f32x4 o0 = zero4, o1 = zero4;
        for (int ch = 0; ch < 11; ch++) {
#pragma unroll
            for (int t = 0; t < 2; t++) {
                int key = ch * 32 + t * 16 + l16;
                const short8 kb = *(const short8*)(Ks + key * 40 + (quad << 3));
                f32x4 s = __builtin_amdgcn_mfma_f32_16x16x32_bf16(qa[i], kb, zero4, 0, 0, 0);
                ushort4 bt = *(const ushort4*)(biasTp + (size_t)key * NPAD + q0);
                ushort4 mk = *(const ushort4*)(maskTp + (size_t)key * NPAD + q0);
                float p0 = __expf(s[0] + bf2f(bt.x) + bf2f(mk.x));
                float p1 = __expf(s[1] + bf2f(bt.y) + bf2f(mk.y));
                float p2 = __expf(s[2] + bf2f(bt.z) + bf2f(mk.z));
                float p3 = __expf(s[3] + bf2f(bt.w) + bf2f(mk.w));
                if (key >= NTOK) { p0 = 0.f; p1 = 0.f; p2 = 0.f; p3 = 0.f; }  // pad keys
                rp[0] += p0; rp[1] += p1; rp[2] += p2; rp[3] += p3;
                unsigned short* pw = P + t * 16 + l16;
                pw[((quad << 2) + 0) * 48] = f2bf(p0);
                pw[((quad << 2) + 1) * 48] = f2bf(p1);
                pw[((quad << 2) + 2) * 48] = f2bf(p2);
                pw[((quad << 2) + 3) * 48] = f2bf(p3);
            }
            const short8 pa = *(const short8*)(P + l16 * 48 + (quad << 3));
            const short8 v0 = *(const short8*)(Vt + l16 * 360 + ch * 32 + (quad << 3));
            const short8 v1 = *(const short8*)(Vt + (16 + l16) * 360 + ch * 32 + (quad << 3));
            o0 = __builtin_amdgcn_mfma_f32_16x16x32_bf16(pa, v0, o0, 0, 0, 0);
            o1 = __builtin_amdgcn_mfma_f32_16x16x32_bf16(pa, v1, o1, 0, 0, 0);
        }
        // reduce row sums across the 16 col-lanes (xor bits 0..3 stay in-quad)
#pragma unroll
        for (int mm = 1; mm <= 8; mm <<= 1) {
            rp[0] += __shfl_xor(rp[0], mm);
            rp[1] += __shfl_xor(rp[1], mm);
            rp[2] += __shfl_xor(rp[2], mm);
            rp[3] += __shfl_xor(rp[3], mm);
        }
#pragma unroll
        for (int r = 0; r < 4; r++) {
            int n = mt * 16 + (quad << 2) + r;
            if (n < NTOK) {
                float inv = 1.f / rp[r];
                size_t base = ((size_t)b * NTOK + n) * CEMB + h * 32;
                attnb[base + l16] = f2bf(o0[r] * inv);
                attnb[base + 16 + l16] = f2bf(o1[r] * inv);
            }
        }
    }
}

// ---------------- output projection: out = attn @ proj_w^T + proj_b ----------------
__global__ __launch_bounds__(256, 4)
void proj_kernel(const unsigned short* __restrict__ attnb, const unsigned short* __restrict__ pwb,
                 const float* __restrict__ proj_b, float* __restrict__ out) {
    const int tid = threadIdx.x;
    const int wave = tid >> 6, lane = tid & 63;
    const int quad = lane >> 4, l16 = lane & 15;
    const int mt = blockIdx.x * 4 + wave;   // 5488 M-tiles total, exact
    const f32x4 zero4 = {0.f, 0.f, 0.f, 0.f};
    f32x4 acc[12];
#pragma unroll
    for (int nt = 0; nt < 12; nt++) acc[nt] = zero4;
#pragma unroll
    for (int ks = 0; ks < 6; ks++) {
        const short8 a = *(const short8*)(attnb + ((size_t)mt * 16 + l16) * CEMB + ks * 32 + (quad << 3));
#pragma unroll
        for (int nt = 0; nt < 12; nt++) {
            const short8 bfrag = *(const short8*)(pwb + ((size_t)(nt * 16 + l16)) * CEMB + ks * 32 + (quad << 3));
            acc[nt] = __builtin_amdgcn_mfma_f32_16x16x32_bf16(a, bfrag, acc[nt], 0, 0, 0);
        }
    }
#pragma unroll
    for (int nt = 0; nt < 12; nt++) {
        float bias = proj_b[nt * 16 + l16];
#pragma unroll
        for (int r = 0; r < 4; r++) {
            int m = mt * 16 + (quad << 2) + r;
            out[(size_t)m * CEMB + nt * 16 + l16] = acc[nt][r] + bias;
        }
    }
}

// ---------------- launch ----------------
extern "C" void kernel_launch(void* const* d_in, const int* in_sizes, int n_in,
                              void* d_out, int out_size, void* d_ws, size_t ws_size,
                              hipStream_t stream) {
    (void)in_sizes; (void)n_in; (void)out_size; (void)ws_size;
    const float* x_in    = (const float*)d_in[0];
    const float* x_cross = (const float*)d_in[1];
    const float* mask    = (const float*)d_in[2];
    const float* q_w     = (const float*)d_in[3];
    const float* kv_w    = (const float*)d_in[4];
    const float* proj_w  = (const float*)d_in[5];
    const float* proj_b  = (const float*)d_in[6];
    const float* btab    = (const float*)d_in[7];
    const int*   rel     = (const int*)d_in[8];
    float* out = (float*)d_out;
    char* ws = (char*)d_ws;

    // ws layout (bytes), total 155,955,200:
    unsigned short* qwb   = (unsigned short*)(ws + 0);           //     73,728
    unsigned short* kvwb  = (unsigned short*)(ws + 73728);       //    147,456
    unsigned short* pwb   = (unsigned short*)(ws + 221184);      //     73,728
    unsigned short* biasT = (unsigned short*)(ws + 294912);      //  1,486,848
    unsigned short* maskT = (unsigned short*)(ws + 1781760);     // 15,859,712
    unsigned short* attnb = (unsigned short*)(ws + 17641472);    // 33,718,272
    unsigned short* Qb    = (unsigned short*)(ws + 51359744);    // 34,603,008
    unsigned short* Kb    = (unsigned short*)(ws + 85962752);    // 34,603,008
    unsigned short* Vtb   = (unsigned short*)(ws + 120565760);   // 35,389,440

    prep_weights<<<576, 256, 0, stream>>>(q_w, kv_w, proj_w, qwb, kvwb, pwb);
    prep_biasT<<<121, 256, 0, stream>>>(btab, rel, biasT);
    prep_maskT<<<64 * 121, 256, 0, stream>>>(mask, maskT);
    qkv_kernel<<<NB * 3, 512, 76800, stream>>>(x_in, x_cross, qwb, kvwb, Qb, Kb, Vtb);
    attn_kernel<<<NB * NH, 512, 63488, stream>>>(Qb, Kb, Vtb, biasT, maskT, attnb);
    proj_kernel<<<5488 / 4, 256, 0, stream>>>(attnb, pwb, proj_b, out);
}

// Round 2
// 419.785 us; speedup vs baseline: 1.4016x; 1.1219x over previous
//
#include <hip/hip_runtime.h>

// Problem constants
#define NTOK 343   // tokens per window (7*7*7)
#define NPAD 352   // 22 * 16
#define CEMB 192
#define NH   6
#define HD   32
#define NB   256
#define NWIN 64

typedef __attribute__((ext_vector_type(8))) short short8;   // 8 x bf16 bits
typedef __attribute__((ext_vector_type(4))) float f32x4;
typedef __attribute__((ext_vector_type(4))) unsigned int uint4v;

__device__ __forceinline__ unsigned short f2bf(float f) {
    unsigned int u = __builtin_bit_cast(unsigned int, f);
    u += 0x7fffu + ((u >> 16) & 1u);          // round-to-nearest-even
    return (unsigned short)(u >> 16);
}
__device__ __forceinline__ float bf2f(unsigned short h) {
    unsigned int u = ((unsigned int)h) << 16;
    return __builtin_bit_cast(float, u);
}
__device__ __forceinline__ short8 pack8(float4 f0, float4 f1) {
    short8 r;
    r[0] = (short)f2bf(f0.x); r[1] = (short)f2bf(f0.y);
    r[2] = (short)f2bf(f0.z); r[3] = (short)f2bf(f0.w);
    r[4] = (short)f2bf(f1.x); r[5] = (short)f2bf(f1.y);
    r[6] = (short)f2bf(f1.z); r[7] = (short)f2bf(f1.w);
    return r;
}
__device__ __forceinline__ unsigned int cvt_pk_bf16(float lo, float hi) {
    unsigned int r;
    asm("v_cvt_pk_bf16_f32 %0, %1, %2" : "=v"(r) : "v"(lo), "v"(hi));
    return r;
}

// ---------------- prep: weights -> bf16 (scale folded into qw) ----------------
__global__ void prep_weights(const float* __restrict__ qw, const float* __restrict__ kvw,
                             const float* __restrict__ pw,
                             unsigned short* __restrict__ qwb, unsigned short* __restrict__ kvwb,
                             unsigned short* __restrict__ pwb) {
    const float scale = 0.17677669529663689f;   // 32^-0.5 folded into Q weights
    int idx = blockIdx.x * 256 + threadIdx.x;
    if (idx < 36864)        qwb[idx] = f2bf(qw[idx] * scale);
    else if (idx < 110592)  kvwb[idx - 36864] = f2bf(kvw[idx - 36864]);
    else if (idx < 147456)  pwb[idx - 110592] = f2bf(pw[idx - 110592]);
}

// ---------------- prep: biasN[h][q][k] (bf16, padded to 352x352, natural layout) -----
__global__ void prep_biasN(const float* __restrict__ table, const int* __restrict__ rel,
                           unsigned short* __restrict__ biasN) {
    __shared__ int sidx[32 * 33];
    int bid = blockIdx.x;                  // 121 blocks: qt*11 + kt
    int qt = bid / 11, kt = bid - qt * 11;
    int q0 = qt * 32, k0 = kt * 32;
    for (int e = threadIdx.x; e < 1024; e += 256) {
        int i = e >> 5, j = e & 31;        // i: q-local, j: k-local
        int q = q0 + i, k = k0 + j;
        sidx[i * 33 + j] = (q < NTOK && k < NTOK) ? rel[q * NTOK + k] : -1;
    }
    __syncthreads();
    for (int h = 0; h < NH; h++) {
        for (int e = threadIdx.x; e < 1024; e += 256) {
            int qq = e >> 5, kk = e & 31;
            int idx = sidx[qq * 33 + kk];
            float v = (idx >= 0) ? table[idx * NH + h] : 0.f;
            biasN[((size_t)h * NPAD + (q0 + qq)) * NPAD + (k0 + kk)] = f2bf(v);
        }
    }
}

// ---------------- prep: maskN[w][q][k] (bf16, padded, natural layout) ----------------
__global__ void prep_maskN(const float* __restrict__ mask, unsigned short* __restrict__ maskN) {
    int idx = blockIdx.x * 256 + threadIdx.x;     // 64*352*352 = 30976*256 exact
    int w = idx / (NPAD * NPAD);
    int rem = idx - w * (NPAD * NPAD);
    int q = rem / NPAD, k = rem - q * NPAD;
    float v = (q < NTOK && k < NTOK) ? mask[((size_t)w * NTOK + q) * NTOK + k] : 0.f;
    maskN[idx] = f2bf(v);
}

// ---------------- QKV projection GEMM ----------------
// One block per (b, o) with o in {Q, K, V}. Weights staged once into padded LDS
// ([192][200] shorts, 76.8 KB -> 2 blocks/CU); B-frags via ds_read_b128.
__global__ __launch_bounds__(512, 2)
void qkv_kernel(const float* __restrict__ x_in, const float* __restrict__ x_cross,
                const unsigned short* __restrict__ qwb, const unsigned short* __restrict__ kvwb,
                unsigned short* __restrict__ Qb, unsigned short* __restrict__ Kb,
                unsigned short* __restrict__ Vtb) {
    extern __shared__ char smem[];
    unsigned short* Ws = (unsigned short*)smem;      // [192][200] padded
    const int tid = threadIdx.x;
    const int wave = tid >> 6, lane = tid & 63;
    const int quad = lane >> 4, l16 = lane & 15;
    const int b = blockIdx.x / 3, o = blockIdx.x % 3;
    const float* xsrc = (o == 0) ? x_in : x_cross;
    const unsigned short* wsrc = (o == 0) ? qwb : (o == 1 ? kvwb : (kvwb + 192 * CEMB));
    const f32x4 zero4 = {0.f, 0.f, 0.f, 0.f};

    for (int i = tid; i < 4608; i += 512) {
        int r = i / 24, c8 = i - r * 24;
        *(short8*)(Ws + r * 200 + c8 * 8) = *(const short8*)(wsrc + (size_t)r * CEMB + c8 * 8);
    }
    __syncthreads();

    for (int mi = 0; mi < 3; mi++) {
        int mt = wave + (mi << 3);
        if (mt >= 22) continue;            // wave-uniform
        int row = mt * 16 + l16;
        f32x4 acc[12];
#pragma unroll
        for (int nt = 0; nt < 12; nt++) acc[nt] = zero4;
#pragma unroll
        for (int kc = 0; kc < 6; kc++) {
            short8 a = {};
            if (row < NTOK) {
                const float* xp = xsrc + ((size_t)b * NTOK + row) * CEMB + kc * 32 + (quad << 3);
                float4 f0 = *(const float4*)xp;
                float4 f1 = *(const float4*)(xp + 4);
                a = pack8(f0, f1);
            }
#pragma unroll
            for (int nt = 0; nt < 12; nt++) {
                const short8 bf = *(const short8*)(Ws + (nt * 16 + l16) * 200 + kc * 32 + (quad << 3));
                acc[nt] = __builtin_amdgcn_mfma_f32_16x16x32_bf16(a, bf, acc[nt], 0, 0, 0);
            }
        }
        if (o < 2) {
            unsigned short* dst = (o == 0 ? Qb : Kb) + (size_t)b * NPAD * CEMB;
#pragma unroll
            for (int nt = 0; nt < 12; nt++) {
#pragma unroll
                for (int r = 0; r < 4; r++) {
                    int m = mt * 16 + (quad << 2) + r;
                    dst[(size_t)m * CEMB + nt * 16 + l16] = f2bf(acc[nt][r]);
                }
            }
        } else {
#pragma unroll
            for (int nt = 0; nt < 12; nt++) {
                int h = nt >> 1, d = ((nt & 1) << 4) + l16;
#pragma unroll
                for (int r = 0; r < 4; r++) {
                    int m = mt * 16 + (quad << 2) + r;
                    Vtb[(((size_t)b * NH + h) * 32 + d) * 360 + m] = f2bf(acc[nt][r]);
                }
            }
        }
    }
}

// ---------------- fused attention per (window b, head h) ----------------
// LDS (dynamic, 51200 B): Ks[352][40] @0 (28160), Vt[32][360] @28160 (23040).
// 3 blocks/CU. Swapped QK^T (S^T = mfma(K,Q)) keeps P in registers; the PV
// A-frag is built via cvt_pk_bf16 + a 4x4 u32 cross-quad shuffle transpose.
// No P LDS buffer -> no bank conflicts, no ds round-trip on the critical path.
__global__ __launch_bounds__(512, 6)
void attn_kernel(const unsigned short* __restrict__ Qb, const unsigned short* __restrict__ Kb,
                 const unsigned short* __restrict__ Vtb,
                 const unsigned short* __restrict__ biasN, const unsigned short* __restrict__ maskN,
                 unsigned short* __restrict__ attnb) {
    extern __shared__ char smem[];
    unsigned short* Ks = (unsigned short*)smem;             // [352][40]
    unsigned short* Vt = (unsigned short*)(smem + 28160);   // [32][360]

    const int tid = threadIdx.x;
    const int wave = tid >> 6, lane = tid & 63;
    const int quad = lane >> 4, l16 = lane & 15;
    const int q4 = quad << 2, q8 = quad << 3;
    const int q0b = (lane >> 4) & 1;    // quad bit0
    const int q1b = (lane >> 5) & 1;    // quad bit1
    const int b = blockIdx.x / NH, h = blockIdx.x - (blockIdx.x / NH) * NH;
    const f32x4 zero4 = {0.f, 0.f, 0.f, 0.f};

    // stage K (this head's 32 channels) into A-frag layout [key][40]
    for (int i = tid; i < 1408; i += 512) {
        int key = i >> 2, part = i & 3;
        *(short8*)(Ks + key * 40 + part * 8) =
            *(const short8*)(Kb + ((size_t)b * NPAD + key) * CEMB + h * 32 + part * 8);
    }
    // stage V^T (contiguous copy of this (b,h) plane)
    const unsigned short* vsrc = Vtb + (size_t)(b * NH + h) * 32 * 360;
    for (int i = tid; i < 1440; i += 512) {
        *(short8*)(Vt + i * 8) = *(const short8*)(vsrc + i * 8);
    }
    // per-wave Q B-frags straight from global
    short8 qa[3] = {};
#pragma unroll
    for (int i = 0; i < 3; i++) {
        int mt = wave + (i << 3);
        if (mt < 22)
            qa[i] = *(const short8*)(Qb + ((size_t)b * NPAD + mt * 16 + l16) * CEMB + h * 32 + q8);
    }
    __syncthreads();

    const unsigned short* biasNp = biasN + (size_t)h * NPAD * NPAD;
    const unsigned short* maskNp = maskN + (size_t)(b & 63) * NPAD * NPAD;
#pragma unroll
    for (int i = 0; i < 3; i++) {
        int mt = wave + (i << 3);
        if (mt >= 22) continue;             // wave-uniform, no barriers below
        const int q = mt * 16 + l16;        // this lane's q-column in S^T
        const unsigned short* brow = biasNp + (size_t)q * NPAD;
        const unsigned short* mrow = maskNp + (size_t)q * NPAD;
        float rp = 0.f;
        f32x4 o0 = zero4, o1 = zero4;
        for (int ch = 0; ch < 11; ch++) {
            const int kb_ = ch * 32;
            const short8 k0f = *(const short8*)(Ks + (kb_ + l16) * 40 + q8);
            const short8 k1f = *(const short8*)(Ks + (kb_ + 16 + l16) * 40 + q8);
            // S^T tiles: lane holds S[q=l16][key = kb_ + 16t + q4 + r] in s{t}[r]
            f32x4 s0 = __builtin_amdgcn_mfma_f32_16x16x32_bf16(k0f, qa[i], zero4, 0, 0, 0);
            f32x4 s1 = __builtin_amdgcn_mfma_f32_16x16x32_bf16(k1f, qa[i], zero4, 0, 0, 0);
            const ushort4 bt0 = *(const ushort4*)(brow + kb_ + q4);
            const ushort4 mk0 = *(const ushort4*)(mrow + kb_ + q4);
            const ushort4 bt1 = *(const ushort4*)(brow + kb_ + 16 + q4);
            const ushort4 mk1 = *(const ushort4*)(mrow + kb_ + 16 + q4);
            float p00 = __expf(s0[0] + bf2f(bt0.x) + bf2f(mk0.x));
            float p01 = __expf(s0[1] + bf2f(bt0.y) + bf2f(mk0.y));
            float p02 = __expf(s0[2] + bf2f(bt0.z) + bf2f(mk0.z));
            float p03 = __expf(s0[3] + bf2f(bt0.w) + bf2f(mk0.w));
            float p10 = __expf(s1[0] + bf2f(bt1.x) + bf2f(mk1.x));
            float p11 = __expf(s1[1] + bf2f(bt1.y) + bf2f(mk1.y));
            float p12 = __expf(s1[2] + bf2f(bt1.z) + bf2f(mk1.z));
            float p13 = __expf(s1[3] + bf2f(bt1.w) + bf2f(mk1.w));
            if (ch == 10) {                 // pad keys 343..351 live in the t=1 tile
                if (q4 + 0 >= 7) p10 = 0.f;
                if (q4 + 1 >= 7) p11 = 0.f;
                if (q4 + 2 >= 7) p12 = 0.f;
                if (q4 + 3 >= 7) p13 = 0.f;
            }
            rp += ((p00 + p01) + (p02 + p03)) + ((p10 + p11) + (p12 + p13));
            // pack to bf16 pairs: c[2t+u] = keys {16t + q4 + 2u, +1}
            unsigned int c0 = cvt_pk_bf16(p00, p01);
            unsigned int c1 = cvt_pk_bf16(p02, p03);
            unsigned int c2 = cvt_pk_bf16(p10, p11);
            unsigned int c3 = cvt_pk_bf16(p12, p13);
            // 4x4 u32 transpose across quads -> PV A-frag A[q=l16][k=key q8+j]
            unsigned int pe0 = q1b ? c0 : c2;
            unsigned int pe1 = q1b ? c1 : c3;
            unsigned int sh0 = __shfl_xor(pe0, 32);
            unsigned int sh1 = __shfl_xor(pe1, 32);
            unsigned int t0 = q1b ? sh0 : c0;
            unsigned int t1 = q1b ? sh1 : c1;
            unsigned int t2 = q1b ? c2 : sh0;
            unsigned int t3 = q1b ? c3 : sh1;
            unsigned int pf0 = q0b ? t0 : t2;
            unsigned int pf1 = q0b ? t1 : t3;
            unsigned int u0 = __shfl_xor(pf0, 16);
            unsigned int u1 = __shfl_xor(pf1, 16);
            unsigned int r0 = q0b ? u0 : t0;
            unsigned int r1 = q0b ? u1 : t1;
            unsigned int r2 = q0b ? t2 : u0;
            unsigned int r3 = q0b ? t3 : u1;
            const short8 pa = __builtin_bit_cast(short8, (uint4v){r0, r1, r2, r3});
            const short8 v0 = *(const short8*)(Vt + l16 * 360 + kb_ + q8);
            const short8 v1 = *(const short8*)(Vt + (16 + l16) * 360 + kb_ + q8);
            o0 = __builtin_amdgcn_mfma_f32_16x16x32_bf16(pa, v0, o0, 0, 0, 0);
            o1 = __builtin_amdgcn_mfma_f32_16x16x32_bf16(pa, v1, o1, 0, 0, 0);
        }
        // rp holds this quad's partial key-sum for q=l16; reduce across quads
        rp += __shfl_xor(rp, 16);
        rp += __shfl_xor(rp, 32);
        float inv = 1.f / rp;               // inverse row-sum for q = mt*16 + l16
#pragma unroll
        for (int r = 0; r < 4; r++) {
            // output row n = mt*16 + q4 + r: fetch its inv from lane l16 = q4+r
            float invr = __shfl(inv, (lane & 48) | (q4 + r));
            int n = mt * 16 + q4 + r;
            if (n < NTOK) {
                size_t base = ((size_t)b * NTOK + n) * CEMB + h * 32;
                attnb[base + l16] = f2bf(o0[r] * invr);
                attnb[base + 16 + l16] = f2bf(o1[r] * invr);
            }
        }
    }
}

// ---------------- output projection: out = attn @ proj_w^T + proj_b ----------------
// Weights staged in LDS ([192][200], 76.8 KB); 8 M-tiles per block (1/wave).
__global__ __launch_bounds__(512, 2)
void proj_kernel(const unsigned short* __restrict__ attnb, const unsigned short* __restrict__ pwb,
                 const float* __restrict__ proj_b, float* __restrict__ out) {
    extern __shared__ char smem[];
    unsigned short* Ws = (unsigned short*)smem;   // [192][200] padded
    const int tid = threadIdx.x;
    const int wave = tid >> 6, lane = tid & 63;
    const int quad = lane >> 4, l16 = lane & 15;
    for (int i = tid; i < 4608; i += 512) {
        int r = i / 24, c8 = i - r * 24;
        *(short8*)(Ws + r * 200 + c8 * 8) = *(const short8*)(pwb + (size_t)r * CEMB + c8 * 8);
    }
    float pb[12];
#pragma unroll
    for (int nt = 0; nt < 12; nt++) pb[nt] = proj_b[nt * 16 + l16];
    __syncthreads();

    const int mt = blockIdx.x * 8 + wave;   // 686*8 = 5488 exact
    const f32x4 zero4 = {0.f, 0.f, 0.f, 0.f};
    f32x4 acc[12];
#pragma unroll
    for (int nt = 0; nt < 12; nt++) acc[nt] = zero4;
#pragma unroll
    for (int ks = 0; ks < 6; ks++) {
        const short8 a = *(const short8*)(attnb + ((size_t)mt * 16 + l16) * CEMB + ks * 32 + (quad << 3));
#pragma unroll
        for (int nt = 0; nt < 12; nt++) {
            const short8 bfrag = *(const short8*)(Ws + (nt * 16 + l16) * 200 + ks * 32 + (quad << 3));
            acc[nt] = __builtin_amdgcn_mfma_f32_16x16x32_bf16(a, bfrag, acc[nt], 0, 0, 0);
        }
    }
#pragma unroll
    for (int nt = 0; nt < 12; nt++) {
#pragma unroll
        for (int r = 0; r < 4; r++) {
            int m = mt * 16 + (quad << 2) + r;
            out[(size_t)m * CEMB + nt * 16 + l16] = acc[nt][r] + pb[nt];
        }
    }
}

// ---------------- launch ----------------
extern "C" void kernel_launch(void* const* d_in, const int* in_sizes, int n_in,
                              void* d_out, int out_size, void* d_ws, size_t ws_size,
                              hipStream_t stream) {
    (void)in_sizes; (void)n_in; (void)out_size; (void)ws_size;
    const float* x_in    = (const float*)d_in[0];
    const float* x_cross = (const float*)d_in[1];
    const float* mask    = (const float*)d_in[2];
    const float* q_w     = (const float*)d_in[3];
    const float* kv_w    = (const float*)d_in[4];
    const float* proj_w  = (const float*)d_in[5];
    const float* proj_b  = (const float*)d_in[6];
    const float* btab    = (const float*)d_in[7];
    const int*   rel     = (const int*)d_in[8];
    float* out = (float*)d_out;
    char* ws = (char*)d_ws;

    // ws layout (bytes), total 155,955,200:
    unsigned short* qwb   = (unsigned short*)(ws + 0);           //     73,728
    unsigned short* kvwb  = (unsigned short*)(ws + 73728);       //    147,456
    unsigned short* pwb   = (unsigned short*)(ws + 221184);      //     73,728
    unsigned short* biasN = (unsigned short*)(ws + 294912);      //  1,486,848
    unsigned short* maskN = (unsigned short*)(ws + 1781760);     // 15,859,712
    unsigned short* attnb = (unsigned short*)(ws + 17641472);    // 33,718,272
    unsigned short* Qb    = (unsigned short*)(ws + 51359744);    // 34,603,008
    unsigned short* Kb    = (unsigned short*)(ws + 85962752);    // 34,603,008
    unsigned short* Vtb   = (unsigned short*)(ws + 120565760);   // 35,389,440

    prep_weights<<<576, 256, 0, stream>>>(q_w, kv_w, proj_w, qwb, kvwb, pwb);
    prep_biasN<<<121, 256, 0, stream>>>(btab, rel, biasN);
    prep_maskN<<<30976, 256, 0, stream>>>(mask, maskN);
    qkv_kernel<<<NB * 3, 512, 76800, stream>>>(x_in, x_cross, qwb, kvwb, Qb, Kb, Vtb);
    attn_kernel<<<NB * NH, 512, 51200, stream>>>(Qb, Kb, Vtb, biasN, maskN, attnb);
    proj_kernel<<<686, 512, 76800, stream>>>(attnb, pwb, proj_b, out);
}

// Round 3
// 411.471 us; speedup vs baseline: 1.4299x; 1.0202x over previous
//
#include <hip/hip_runtime.h>

// Problem constants
#define NTOK 343   // tokens per window (7*7*7)
#define NPAD 352   // 22 * 16
#define CEMB 192
#define NH   6
#define HD   32
#define NB   256
#define NWIN 64

typedef __attribute__((ext_vector_type(8))) short short8;   // 8 x bf16 bits
typedef __attribute__((ext_vector_type(4))) float f32x4;
typedef __attribute__((ext_vector_type(4))) unsigned int uint4v;
typedef __attribute__((ext_vector_type(2))) unsigned int uint2v;

__device__ __forceinline__ unsigned short f2bf(float f) {
    unsigned int u = __builtin_bit_cast(unsigned int, f);
    u += 0x7fffu + ((u >> 16) & 1u);          // round-to-nearest-even
    return (unsigned short)(u >> 16);
}
__device__ __forceinline__ float bf2f(unsigned short h) {
    unsigned int u = ((unsigned int)h) << 16;
    return __builtin_bit_cast(float, u);
}
__device__ __forceinline__ short8 pack8(float4 f0, float4 f1) {
    short8 r;
    r[0] = (short)f2bf(f0.x); r[1] = (short)f2bf(f0.y);
    r[2] = (short)f2bf(f0.z); r[3] = (short)f2bf(f0.w);
    r[4] = (short)f2bf(f1.x); r[5] = (short)f2bf(f1.y);
    r[6] = (short)f2bf(f1.z); r[7] = (short)f2bf(f1.w);
    return r;
}
__device__ __forceinline__ unsigned int cvt_pk_bf16(float lo, float hi) {
    unsigned int r;
    asm("v_cvt_pk_bf16_f32 %0, %1, %2" : "=v"(r) : "v"(lo), "v"(hi));
    return r;
}

#define LOG2E 1.4426950408889634f

// ---------------- prep: weights -> bf16 (scale * log2e folded into qw) ----------------
__global__ void prep_weights(const float* __restrict__ qw, const float* __restrict__ kvw,
                             const float* __restrict__ pw,
                             unsigned short* __restrict__ qwb, unsigned short* __restrict__ kvwb,
                             unsigned short* __restrict__ pwb) {
    const float scale = 0.17677669529663689f * LOG2E;   // 32^-0.5 * log2(e), for exp2 softmax
    int idx = blockIdx.x * 256 + threadIdx.x;
    if (idx < 36864)        qwb[idx] = f2bf(qw[idx] * scale);
    else if (idx < 110592)  kvwb[idx - 36864] = f2bf(kvw[idx - 36864]);
    else if (idx < 147456)  pwb[idx - 110592] = f2bf(pw[idx - 110592]);
}

// ---------------- prep: biasN[h][q][k] (bf16 * log2e, padded to 352x352) -----
__global__ void prep_biasN(const float* __restrict__ table, const int* __restrict__ rel,
                           unsigned short* __restrict__ biasN) {
    __shared__ int sidx[32 * 33];
    int bid = blockIdx.x;                  // 121 blocks: qt*11 + kt
    int qt = bid / 11, kt = bid - qt * 11;
    int q0 = qt * 32, k0 = kt * 32;
    for (int e = threadIdx.x; e < 1024; e += 256) {
        int i = e >> 5, j = e & 31;        // i: q-local, j: k-local
        int q = q0 + i, k = k0 + j;
        sidx[i * 33 + j] = (q < NTOK && k < NTOK) ? rel[q * NTOK + k] : -1;
    }
    __syncthreads();
    for (int h = 0; h < NH; h++) {
        for (int e = threadIdx.x; e < 1024; e += 256) {
            int qq = e >> 5, kk = e & 31;
            int idx = sidx[qq * 33 + kk];
            float v = (idx >= 0) ? table[idx * NH + h] * LOG2E : 0.f;
            biasN[((size_t)h * NPAD + (q0 + qq)) * NPAD + (k0 + kk)] = f2bf(v);
        }
    }
}

// ---------------- prep: maskN[w][q][k] (bf16 * log2e, padded) ----------------
__global__ void prep_maskN(const float* __restrict__ mask, unsigned short* __restrict__ maskN) {
    int idx = blockIdx.x * 256 + threadIdx.x;     // 64*352*352 = 30976*256 exact
    int w = idx / (NPAD * NPAD);
    int rem = idx - w * (NPAD * NPAD);
    int q = rem / NPAD, k = rem - q * NPAD;
    float v = (q < NTOK && k < NTOK) ? mask[((size_t)w * NTOK + q) * NTOK + k] * LOG2E : 0.f;
    maskN[idx] = f2bf(v);
}

// ---------------- QKV projection GEMM ----------------
// One block per (b, o) with o in {Q, K, V}. Weights staged once into padded LDS
// ([192][200] shorts, 76.8 KB -> 2 blocks/CU); B-frags via ds_read_b128.
__global__ __launch_bounds__(512, 2)
void qkv_kernel(const float* __restrict__ x_in, const float* __restrict__ x_cross,
                const unsigned short* __restrict__ qwb, const unsigned short* __restrict__ kvwb,
                unsigned short* __restrict__ Qb, unsigned short* __restrict__ Kb,
                unsigned short* __restrict__ Vtb) {
    extern __shared__ char smem[];
    unsigned short* Ws = (unsigned short*)smem;      // [192][200] padded
    const int tid = threadIdx.x;
    const int wave = tid >> 6, lane = tid & 63;
    const int quad = lane >> 4, l16 = lane & 15;
    const int b = blockIdx.x / 3, o = blockIdx.x % 3;
    const float* xsrc = (o == 0) ? x_in : x_cross;
    const unsigned short* wsrc = (o == 0) ? qwb : (o == 1 ? kvwb : (kvwb + 192 * CEMB));
    const f32x4 zero4 = {0.f, 0.f, 0.f, 0.f};

    for (int i = tid; i < 4608; i += 512) {
        int r = i / 24, c8 = i - r * 24;
        *(short8*)(Ws + r * 200 + c8 * 8) = *(const short8*)(wsrc + (size_t)r * CEMB + c8 * 8);
    }
    __syncthreads();

    for (int mi = 0; mi < 3; mi++) {
        int mt = wave + (mi << 3);
        if (mt >= 22) continue;            // wave-uniform
        int row = mt * 16 + l16;
        f32x4 acc[12];
#pragma unroll
        for (int nt = 0; nt < 12; nt++) acc[nt] = zero4;
#pragma unroll
        for (int kc = 0; kc < 6; kc++) {
            short8 a = {};
            if (row < NTOK) {
                const float* xp = xsrc + ((size_t)b * NTOK + row) * CEMB + kc * 32 + (quad << 3);
                float4 f0 = *(const float4*)xp;
                float4 f1 = *(const float4*)(xp + 4);
                a = pack8(f0, f1);
            }
#pragma unroll
            for (int nt = 0; nt < 12; nt++) {
                const short8 bf = *(const short8*)(Ws + (nt * 16 + l16) * 200 + kc * 32 + (quad << 3));
                acc[nt] = __builtin_amdgcn_mfma_f32_16x16x32_bf16(a, bf, acc[nt], 0, 0, 0);
            }
        }
        if (o < 2) {
            unsigned short* dst = (o == 0 ? Qb : Kb) + (size_t)b * NPAD * CEMB;
#pragma unroll
            for (int nt = 0; nt < 12; nt++) {
#pragma unroll
                for (int r = 0; r < 4; r++) {
                    int m = mt * 16 + (quad << 2) + r;
                    dst[(size_t)m * CEMB + nt * 16 + l16] = f2bf(acc[nt][r]);
                }
            }
        } else {
#pragma unroll
            for (int nt = 0; nt < 12; nt++) {
                int h = nt >> 1, d = ((nt & 1) << 4) + l16;
#pragma unroll
                for (int r = 0; r < 4; r++) {
                    int m = mt * 16 + (quad << 2) + r;
                    Vtb[(((size_t)b * NH + h) * 32 + d) * 360 + m] = f2bf(acc[nt][r]);
                }
            }
        }
    }
}

// ---------------- fused attention per (window b, head h) ----------------
// LDS (dynamic, 51200 B): Ks[352][40] @0 (28160), Vt[32][360] @28160 (23040).
// 3 blocks/CU. Swapped QK^T (S^T = mfma(K,Q)) keeps P in registers; the PV
// A-frag is built via cvt_pk_bf16 + permlane32_swap/permlane16_swap (pure VALU,
// no LDS pipe). bias/mask loads software-pipelined one chunk ahead. Blocks are
// XCD-swizzled so the 24 blocks sharing a mask plane (and 4 b's of Q/K/V) land
// on one XCD's L2.
__global__ __launch_bounds__(512, 6)
void attn_kernel(const unsigned short* __restrict__ Qb, const unsigned short* __restrict__ Kb,
                 const unsigned short* __restrict__ Vtb,
                 const unsigned short* __restrict__ biasN, const unsigned short* __restrict__ maskN,
                 unsigned short* __restrict__ attnb) {
    extern __shared__ char smem[];
    unsigned short* Ks = (unsigned short*)smem;             // [352][40]
    unsigned short* Vt = (unsigned short*)(smem + 28160);   // [32][360]

    const int tid = threadIdx.x;
    const int wave = tid >> 6, lane = tid & 63;
    const int quad = lane >> 4, l16 = lane & 15;
    const int q4 = quad << 2, q8 = quad << 3;
    // XCD-aware swizzle: physical p -> XCD p%8 owns 192 consecutive logical blocks;
    // logical order (w, b>>6, h): 24 consecutive blocks share one mask plane.
    const int p = blockIdx.x;
    const int L = (p & 7) * 192 + (p >> 3);
    const int w = L / 24, r_ = L - w * 24;
    const int b = (r_ / 6) * 64 + w;
    const int h = r_ - (r_ / 6) * 6;
    const f32x4 zero4 = {0.f, 0.f, 0.f, 0.f};

    // stage K (this head's 32 channels) into A-frag layout [key][40]
    for (int i = tid; i < 1408; i += 512) {
        int key = i >> 2, part = i & 3;
        *(short8*)(Ks + key * 40 + part * 8) =
            *(const short8*)(Kb + ((size_t)b * NPAD + key) * CEMB + h * 32 + part * 8);
    }
    // stage V^T (contiguous copy of this (b,h) plane)
    const unsigned short* vsrc = Vtb + (size_t)(b * NH + h) * 32 * 360;
    for (int i = tid; i < 1440; i += 512) {
        *(short8*)(Vt + i * 8) = *(const short8*)(vsrc + i * 8);
    }
    // per-wave Q B-frags straight from global
    short8 qa[3] = {};
#pragma unroll
    for (int i = 0; i < 3; i++) {
        int mt = wave + (i << 3);
        if (mt < 22)
            qa[i] = *(const short8*)(Qb + ((size_t)b * NPAD + mt * 16 + l16) * CEMB + h * 32 + q8);
    }
    __syncthreads();

    const unsigned short* biasNp = biasN + (size_t)h * NPAD * NPAD;
    const unsigned short* maskNp = maskN + (size_t)w * NPAD * NPAD;
#pragma unroll
    for (int i = 0; i < 3; i++) {
        int mt = wave + (i << 3);
        if (mt >= 22) continue;             // wave-uniform, no barriers below
        const int q = mt * 16 + l16;        // this lane's q-column in S^T
        const unsigned short* brow = biasNp + (size_t)q * NPAD;
        const unsigned short* mrow = maskNp + (size_t)q * NPAD;
        float rp = 0.f;
        f32x4 o0 = zero4, o1 = zero4;
        // software-pipeline prologue: bias/mask for chunk 0
        ushort4 bt0c = *(const ushort4*)(brow + q4);
        ushort4 mk0c = *(const ushort4*)(mrow + q4);
        ushort4 bt1c = *(const ushort4*)(brow + 16 + q4);
        ushort4 mk1c = *(const ushort4*)(mrow + 16 + q4);
        for (int ch = 0; ch < 11; ch++) {
            const int kb_ = ch * 32;
            const int kbn = (ch < 10) ? kb_ + 32 : kb_;   // last iter: harmless reload
            // issue next chunk's bias/mask loads early (hide L2/L3 latency)
            ushort4 bt0n = *(const ushort4*)(brow + kbn + q4);
            ushort4 mk0n = *(const ushort4*)(mrow + kbn + q4);
            ushort4 bt1n = *(const ushort4*)(brow + kbn + 16 + q4);
            ushort4 mk1n = *(const ushort4*)(mrow + kbn + 16 + q4);
            const short8 k0f = *(const short8*)(Ks + (kb_ + l16) * 40 + q8);
            const short8 k1f = *(const short8*)(Ks + (kb_ + 16 + l16) * 40 + q8);
            // S^T tiles: lane holds S[q=l16][key = kb_ + 16t + q4 + r] in s{t}[r]
            f32x4 s0 = __builtin_amdgcn_mfma_f32_16x16x32_bf16(k0f, qa[i], zero4, 0, 0, 0);
            f32x4 s1 = __builtin_amdgcn_mfma_f32_16x16x32_bf16(k1f, qa[i], zero4, 0, 0, 0);
            float p00 = __builtin_amdgcn_exp2f(s0[0] + bf2f(bt0c.x) + bf2f(mk0c.x));
            float p01 = __builtin_amdgcn_exp2f(s0[1] + bf2f(bt0c.y) + bf2f(mk0c.y));
            float p02 = __builtin_amdgcn_exp2f(s0[2] + bf2f(bt0c.z) + bf2f(mk0c.z));
            float p03 = __builtin_amdgcn_exp2f(s0[3] + bf2f(bt0c.w) + bf2f(mk0c.w));
            float p10 = __builtin_amdgcn_exp2f(s1[0] + bf2f(bt1c.x) + bf2f(mk1c.x));
            float p11 = __builtin_amdgcn_exp2f(s1[1] + bf2f(bt1c.y) + bf2f(mk1c.y));
            float p12 = __builtin_amdgcn_exp2f(s1[2] + bf2f(bt1c.z) + bf2f(mk1c.z));
            float p13 = __builtin_amdgcn_exp2f(s1[3] + bf2f(bt1c.w) + bf2f(mk1c.w));
            if (ch == 10) {                 // pad keys 343..351 live in the t=1 tile
                if (q4 + 0 >= 7) p10 = 0.f;
                if (q4 + 1 >= 7) p11 = 0.f;
                if (q4 + 2 >= 7) p12 = 0.f;
                if (q4 + 3 >= 7) p13 = 0.f;
            }
            rp += ((p00 + p01) + (p02 + p03)) + ((p10 + p11) + (p12 + p13));
            // pack to bf16 pairs: c0=keys(q4,q4+1) c1=(q4+2,q4+3) [t=0]; c2,c3 same [t=1]
            unsigned int c0 = cvt_pk_bf16(p00, p01);
            unsigned int c1 = cvt_pk_bf16(p02, p03);
            unsigned int c2 = cvt_pk_bf16(p10, p11);
            unsigned int c3 = cvt_pk_bf16(p12, p13);
            // 4x4 u32 cross-quad transpose via permlane swaps (VALU only):
            // swap32: a' = [a.lo|b.lo], b' = [a.hi|b.hi]; then swap16 within halves.
            uint2v sa = __builtin_amdgcn_permlane32_swap(c0, c2, false, false);
            uint2v sb = __builtin_amdgcn_permlane32_swap(c1, c3, false, false);
            uint2v ta = __builtin_amdgcn_permlane16_swap(sa[0], sa[1], false, false);
            uint2v tb = __builtin_amdgcn_permlane16_swap(sb[0], sb[1], false, false);
            // PV A-frag: A[q=l16][key kb_ + q8 + j], j=0..7
            const short8 pa = __builtin_bit_cast(short8, (uint4v){ta[0], tb[0], ta[1], tb[1]});
            const short8 v0 = *(const short8*)(Vt + l16 * 360 + kb_ + q8);
            const short8 v1 = *(const short8*)(Vt + (16 + l16) * 360 + kb_ + q8);
            o0 = __builtin_amdgcn_mfma_f32_16x16x32_bf16(pa, v0, o0, 0, 0, 0);
            o1 = __builtin_amdgcn_mfma_f32_16x16x32_bf16(pa, v1, o1, 0, 0, 0);
            bt0c = bt0n; mk0c = mk0n; bt1c = bt1n; mk1c = mk1n;
        }
        // rp holds this quad's partial key-sum for q=l16; reduce across quads
        rp += __shfl_xor(rp, 16);
        rp += __shfl_xor(rp, 32);
        float inv = 1.f / rp;               // inverse row-sum for q = mt*16 + l16
#pragma unroll
        for (int r = 0; r < 4; r++) {
            // output row n = mt*16 + q4 + r: fetch its inv from lane l16 = q4+r
            float invr = __shfl(inv, (lane & 48) | (q4 + r));
            int n = mt * 16 + q4 + r;
            if (n < NTOK) {
                size_t base = ((size_t)b * NTOK + n) * CEMB + h * 32;
                attnb[base + l16] = f2bf(o0[r] * invr);
                attnb[base + 16 + l16] = f2bf(o1[r] * invr);
            }
        }
    }
}

// ---------------- output projection: out = attn @ proj_w^T + proj_b ----------------
// Weights staged in LDS ([192][200], 76.8 KB); 8 M-tiles per block (1/wave).
__global__ __launch_bounds__(512, 2)
void proj_kernel(const unsigned short* __restrict__ attnb, const unsigned short* __restrict__ pwb,
                 const float* __restrict__ proj_b, float* __restrict__ out) {
    extern __shared__ char smem[];
    unsigned short* Ws = (unsigned short*)smem;   // [192][200] padded
    const int tid = threadIdx.x;
    const int wave = tid >> 6, lane = tid & 63;
    const int quad = lane >> 4, l16 = lane & 15;
    for (int i = tid; i < 4608; i += 512) {
        int r = i / 24, c8 = i - r * 24;
        *(short8*)(Ws + r * 200 + c8 * 8) = *(const short8*)(pwb + (size_t)r * CEMB + c8 * 8);
    }
    float pb[12];
#pragma unroll
    for (int nt = 0; nt < 12; nt++) pb[nt] = proj_b[nt * 16 + l16];
    __syncthreads();

    const int mt = blockIdx.x * 8 + wave;   // 686*8 = 5488 exact
    const f32x4 zero4 = {0.f, 0.f, 0.f, 0.f};
    f32x4 acc[12];
#pragma unroll
    for (int nt = 0; nt < 12; nt++) acc[nt] = zero4;
#pragma unroll
    for (int ks = 0; ks < 6; ks++) {
        const short8 a = *(const short8*)(attnb + ((size_t)mt * 16 + l16) * CEMB + ks * 32 + (quad << 3));
#pragma unroll
        for (int nt = 0; nt < 12; nt++) {
            const short8 bfrag = *(const short8*)(Ws + (nt * 16 + l16) * 200 + ks * 32 + (quad << 3));
            acc[nt] = __builtin_amdgcn_mfma_f32_16x16x32_bf16(a, bfrag, acc[nt], 0, 0, 0);
        }
    }
#pragma unroll
    for (int nt = 0; nt < 12; nt++) {
#pragma unroll
        for (int r = 0; r < 4; r++) {
            int m = mt * 16 + (quad << 2) + r;
            out[(size_t)m * CEMB + nt * 16 + l16] = acc[nt][r] + pb[nt];
        }
    }
}

// ---------------- launch ----------------
extern "C" void kernel_launch(void* const* d_in, const int* in_sizes, int n_in,
                              void* d_out, int out_size, void* d_ws, size_t ws_size,
                              hipStream_t stream) {
    (void)in_sizes; (void)n_in; (void)out_size; (void)ws_size;
    const float* x_in    = (const float*)d_in[0];
    const float* x_cross = (const float*)d_in[1];
    const float* mask    = (const float*)d_in[2];
    const float* q_w     = (const float*)d_in[3];
    const float* kv_w    = (const float*)d_in[4];
    const float* proj_w  = (const float*)d_in[5];
    const float* proj_b  = (const float*)d_in[6];
    const float* btab    = (const float*)d_in[7];
    const int*   rel     = (const int*)d_in[8];
    float* out = (float*)d_out;
    char* ws = (char*)d_ws;

    // ws layout (bytes), total 155,955,200:
    unsigned short* qwb   = (unsigned short*)(ws + 0);           //     73,728
    unsigned short* kvwb  = (unsigned short*)(ws + 73728);       //    147,456
    unsigned short* pwb   = (unsigned short*)(ws + 221184);      //     73,728
    unsigned short* biasN = (unsigned short*)(ws + 294912);      //  1,486,848
    unsigned short* maskN = (unsigned short*)(ws + 1781760);     // 15,859,712
    unsigned short* attnb = (unsigned short*)(ws + 17641472);    // 33,718,272
    unsigned short* Qb    = (unsigned short*)(ws + 51359744);    // 34,603,008
    unsigned short* Kb    = (unsigned short*)(ws + 85962752);    // 34,603,008
    unsigned short* Vtb   = (unsigned short*)(ws + 120565760);   // 35,389,440

    prep_weights<<<576, 256, 0, stream>>>(q_w, kv_w, proj_w, qwb, kvwb, pwb);
    prep_biasN<<<121, 256, 0, stream>>>(btab, rel, biasN);
    prep_maskN<<<30976, 256, 0, stream>>>(mask, maskN);
    qkv_kernel<<<NB * 3, 512, 76800, stream>>>(x_in, x_cross, qwb, kvwb, Qb, Kb, Vtb);
    attn_kernel<<<NB * NH, 512, 51200, stream>>>(Qb, Kb, Vtb, biasN, maskN, attnb);
    proj_kernel<<<686, 512, 76800, stream>>>(attnb, pwb, proj_b, out);
}

// Round 4
// 366.977 us; speedup vs baseline: 1.6032x; 1.1212x over previous
//
#include <hip/hip_runtime.h>

// Problem constants
#define NTOK 343   // tokens per window (7*7*7)
#define NPAD 352   // 22 * 16
#define CEMB 192
#define NH   6
#define HD   32
#define NB   256
#define NWIN 64
#define FPLANE 123904   // fragment-plane stride in shorts: 22*11*2*64*4

typedef __attribute__((ext_vector_type(8))) short short8;   // 8 x bf16 bits
typedef __attribute__((ext_vector_type(4))) float f32x4;
typedef __attribute__((ext_vector_type(4))) unsigned int uint4v;
typedef __attribute__((ext_vector_type(2))) unsigned int uint2v;

__device__ __forceinline__ unsigned short f2bf(float f) {
    unsigned int u = __builtin_bit_cast(unsigned int, f);
    u += 0x7fffu + ((u >> 16) & 1u);          // round-to-nearest-even
    return (unsigned short)(u >> 16);
}
__device__ __forceinline__ float bf2f(unsigned short h) {
    unsigned int u = ((unsigned int)h) << 16;
    return __builtin_bit_cast(float, u);
}
__device__ __forceinline__ short8 pack8(float4 f0, float4 f1) {
    short8 r;
    r[0] = (short)f2bf(f0.x); r[1] = (short)f2bf(f0.y);
    r[2] = (short)f2bf(f0.z); r[3] = (short)f2bf(f0.w);
    r[4] = (short)f2bf(f1.x); r[5] = (short)f2bf(f1.y);
    r[6] = (short)f2bf(f1.z); r[7] = (short)f2bf(f1.w);
    return r;
}
__device__ __forceinline__ unsigned int cvt_pk_bf16(float lo, float hi) {
    unsigned int r;
    asm("v_cvt_pk_bf16_f32 %0, %1, %2" : "=v"(r) : "v"(lo), "v"(hi));
    return r;
}

#define LOG2E 1.4426950408889634f

// ---------------- prep: weights -> bf16 (scale * log2e folded into qw) ----------------
__global__ void prep_weights(const float* __restrict__ qw, const float* __restrict__ kvw,
                             const float* __restrict__ pw,
                             unsigned short* __restrict__ qwb, unsigned short* __restrict__ kvwb,
                             unsigned short* __restrict__ pwb) {
    const float scale = 0.17677669529663689f * LOG2E;   // 32^-0.5 * log2(e), for exp2 softmax
    int idx = blockIdx.x * 256 + threadIdx.x;
    if (idx < 36864)        qwb[idx] = f2bf(qw[idx] * scale);
    else if (idx < 110592)  kvwb[idx - 36864] = f2bf(kvw[idx - 36864]);
    else if (idx < 147456)  pwb[idx - 110592] = f2bf(pw[idx - 110592]);
}

// ---------------- prep: biasF in MFMA-fragment order ----------------
// biasF[h][mt][ch][t][lane][r] = bias[q = mt*16 + (lane&15)][k = ch*32 + t*16 + ((lane>>4)<<2) + r]
// so the attn kernel loads one coalesced ushort4 per lane (base + lane*8B).
__global__ void prep_biasF(const float* __restrict__ table, const int* __restrict__ rel,
                           unsigned short* __restrict__ biasF) {
    int idx = blockIdx.x * 256 + threadIdx.x;       // 6*22*11*2*64 = 186368 = 728*256 exact
    int lane = idx & 63;
    int rest = idx >> 6;
    int t = rest & 1; rest >>= 1;
    int ch = rest % 11; rest /= 11;
    int mt = rest % 22; int h = rest / 22;
    int q = mt * 16 + (lane & 15);
    int k0 = ch * 32 + t * 16 + ((lane >> 4) << 2);
    ushort4 out;
#pragma unroll
    for (int r = 0; r < 4; r++) {
        int k = k0 + r;
        float v = (q < NTOK && k < NTOK) ? table[rel[q * NTOK + k] * NH + h] * LOG2E : 0.f;
        ((unsigned short*)&out)[r] = f2bf(v);
    }
    *(ushort4*)(biasF + (size_t)idx * 4) = out;
}

// ---------------- prep: maskF in MFMA-fragment order; pad keys = -60000 ----------------
__global__ void prep_maskF(const float* __restrict__ mask, unsigned short* __restrict__ maskF) {
    int idx = blockIdx.x * 256 + threadIdx.x;       // 64*22*11*2*64 = 1982464 = 7744*256 exact
    int lane = idx & 63;
    int rest = idx >> 6;
    int t = rest & 1; rest >>= 1;
    int ch = rest % 11; rest /= 11;
    int mt = rest % 22; int w = rest / 22;
    int q = mt * 16 + (lane & 15);
    int k0 = ch * 32 + t * 16 + ((lane >> 4) << 2);
    ushort4 out;
#pragma unroll
    for (int r = 0; r < 4; r++) {
        int k = k0 + r;
        float v;
        if (k >= NTOK) v = -60000.f;                 // pad key: exp2 -> 0, no branch in attn
        else if (q < NTOK) v = mask[((size_t)w * NTOK + q) * NTOK + k] * LOG2E;
        else v = 0.f;                                // pad q rows: stores are guarded anyway
        ((unsigned short*)&out)[r] = f2bf(v);
    }
    *(ushort4*)(maskF + (size_t)idx * 4) = out;
}

// ---------------- Q projection GEMM (one block per b) ----------------
// Weights staged once into padded LDS ([192][200] shorts, 76.8 KB -> 2 blocks/CU).
__global__ __launch_bounds__(512, 2)
void qkv_q_kernel(const float* __restrict__ x_in, const unsigned short* __restrict__ qwb,
                  unsigned short* __restrict__ Qb) {
    extern __shared__ char smem[];
    unsigned short* Ws = (unsigned short*)smem;      // [192][200] padded
    const int tid = threadIdx.x;
    const int wave = tid >> 6, lane = tid & 63;
    const int quad = lane >> 4, l16 = lane & 15;
    const int b = blockIdx.x;
    const f32x4 zero4 = {0.f, 0.f, 0.f, 0.f};

    for (int i = tid; i < 4608; i += 512) {
        int r = i / 24, c8 = i - r * 24;
        *(short8*)(Ws + r * 200 + c8 * 8) = *(const short8*)(qwb + (size_t)r * CEMB + c8 * 8);
    }
    __syncthreads();

    for (int mi = 0; mi < 3; mi++) {
        int mt = wave + (mi << 3);
        if (mt >= 22) continue;            // wave-uniform
        int row = mt * 16 + l16;
        f32x4 acc[12];
#pragma unroll
        for (int nt = 0; nt < 12; nt++) acc[nt] = zero4;
#pragma unroll
        for (int kc = 0; kc < 6; kc++) {
            short8 a = {};
            if (row < NTOK) {
                const float* xp = x_in + ((size_t)b * NTOK + row) * CEMB + kc * 32 + (quad << 3);
                a = pack8(*(const float4*)xp, *(const float4*)(xp + 4));
            }
#pragma unroll
            for (int nt = 0; nt < 12; nt++) {
                const short8 bf = *(const short8*)(Ws + (nt * 16 + l16) * 200 + kc * 32 + (quad << 3));
                acc[nt] = __builtin_amdgcn_mfma_f32_16x16x32_bf16(a, bf, acc[nt], 0, 0, 0);
            }
        }
        unsigned short* dst = Qb + (size_t)b * NPAD * CEMB;
#pragma unroll
        for (int nt = 0; nt < 12; nt++) {
#pragma unroll
            for (int r = 0; r < 4; r++) {
                int m = mt * 16 + (quad << 2) + r;
                dst[(size_t)m * CEMB + nt * 16 + l16] = f2bf(acc[nt][r]);
            }
        }
    }
}

// ---------------- K+V projection GEMM (one block per b) ----------------
// x_cross A-frags packed ONCE into registers (18 short8) and reused for both
// K and V passes; kw then vw staged into the same 76.8 KB LDS. Eliminates the
// duplicate x_cross HBM read and half the pack8 VALU of the old 3-way split.
__global__ __launch_bounds__(512, 2)
void qkv_kv_kernel(const float* __restrict__ x_cross, const unsigned short* __restrict__ kvwb,
                   unsigned short* __restrict__ Kb, unsigned short* __restrict__ Vtb) {
    extern __shared__ char smem[];
    unsigned short* Ws = (unsigned short*)smem;      // [192][200] padded
    const int tid = threadIdx.x;
    const int wave = tid >> 6, lane = tid & 63;
    const int quad = lane >> 4, l16 = lane & 15;
    const int b = blockIdx.x;
    const f32x4 zero4 = {0.f, 0.f, 0.f, 0.f};

    // stage K weights (kvw rows 0..191)
    for (int i = tid; i < 4608; i += 512) {
        int r = i / 24, c8 = i - r * 24;
        *(short8*)(Ws + r * 200 + c8 * 8) = *(const short8*)(kvwb + (size_t)r * CEMB + c8 * 8);
    }

    // pack all A-frags (held in registers across both passes)
    short8 a[3][6];
#pragma unroll
    for (int mi = 0; mi < 3; mi++) {
        int mt = wave + (mi << 3);
        int row = mt * 16 + l16;
#pragma unroll
        for (int kc = 0; kc < 6; kc++) {
            a[mi][kc] = (short8){};
            if (mt < 22 && row < NTOK) {
                const float* xp = x_cross + ((size_t)b * NTOK + row) * CEMB + kc * 32 + (quad << 3);
                a[mi][kc] = pack8(*(const float4*)xp, *(const float4*)(xp + 4));
            }
        }
    }
    __syncthreads();

    // ---- K pass ----
#pragma unroll
    for (int mi = 0; mi < 3; mi++) {
        int mt = wave + (mi << 3);
        if (mt >= 22) continue;
        f32x4 acc[12];
#pragma unroll
        for (int nt = 0; nt < 12; nt++) acc[nt] = zero4;
#pragma unroll
        for (int kc = 0; kc < 6; kc++) {
#pragma unroll
            for (int nt = 0; nt < 12; nt++) {
                const short8 bf = *(const short8*)(Ws + (nt * 16 + l16) * 200 + kc * 32 + (quad << 3));
                acc[nt] = __builtin_amdgcn_mfma_f32_16x16x32_bf16(a[mi][kc], bf, acc[nt], 0, 0, 0);
            }
        }
        unsigned short* dst = Kb + (size_t)b * NPAD * CEMB;
#pragma unroll
        for (int nt = 0; nt < 12; nt++) {
#pragma unroll
            for (int r = 0; r < 4; r++) {
                int m = mt * 16 + (quad << 2) + r;
                dst[(size_t)m * CEMB + nt * 16 + l16] = f2bf(acc[nt][r]);
            }
        }
    }
    __syncthreads();
    // stage V weights (kvw rows 192..383)
    for (int i = tid; i < 4608; i += 512) {
        int r = i / 24, c8 = i - r * 24;
        *(short8*)(Ws + r * 200 + c8 * 8) = *(const short8*)(kvwb + (size_t)(192 + r) * CEMB + c8 * 8);
    }
    __syncthreads();

    // ---- V pass (reuses held A-frags) ----
#pragma unroll
    for (int mi = 0; mi < 3; mi++) {
        int mt = wave + (mi << 3);
        if (mt >= 22) continue;
        f32x4 acc[12];
#pragma unroll
        for (int nt = 0; nt < 12; nt++) acc[nt] = zero4;
#pragma unroll
        for (int kc = 0; kc < 6; kc++) {
#pragma unroll
            for (int nt = 0; nt < 12; nt++) {
                const short8 bf = *(const short8*)(Ws + (nt * 16 + l16) * 200 + kc * 32 + (quad << 3));
                acc[nt] = __builtin_amdgcn_mfma_f32_16x16x32_bf16(a[mi][kc], bf, acc[nt], 0, 0, 0);
            }
        }
#pragma unroll
        for (int nt = 0; nt < 12; nt++) {
            int h = nt >> 1, d = ((nt & 1) << 4) + l16;
#pragma unroll
            for (int r = 0; r < 4; r++) {
                int m = mt * 16 + (quad << 2) + r;
                Vtb[(((size_t)b * NH + h) * 32 + d) * 360 + m] = f2bf(acc[nt][r]);
            }
        }
    }
}

// ---------------- fused attention per (window b, head h) ----------------
// LDS (51200 B): Ks[352][40] @0, Vt[32][360] @28160. 3 blocks/CU.
// Swapped QK^T (S^T = mfma(K,Q)); bias+mask enter as the MFMA C operand
// (coalesced fragment-ordered tables, pad keys = -60000 -> exp2 = 0, no
// branches); P stays in registers via cvt_pk + permlane swaps; XCD-swizzled.
__global__ __launch_bounds__(512, 6)
void attn_kernel(const unsigned short* __restrict__ Qb, const unsigned short* __restrict__ Kb,
                 const unsigned short* __restrict__ Vtb,
                 const unsigned short* __restrict__ biasF, const unsigned short* __restrict__ maskF,
                 unsigned short* __restrict__ attnb) {
    extern __shared__ char smem[];
    unsigned short* Ks = (unsigned short*)smem;             // [352][40]
    unsigned short* Vt = (unsigned short*)(smem + 28160);   // [32][360]

    const int tid = threadIdx.x;
    const int wave = tid >> 6, lane = tid & 63;
    const int quad = lane >> 4, l16 = lane & 15;
    const int q4 = quad << 2, q8 = quad << 3;
    // XCD-aware swizzle: physical p -> XCD p%8 owns 192 consecutive logical blocks;
    // logical order (w, b>>6, h): 24 consecutive blocks share one mask plane.
    const int p = blockIdx.x;
    const int L = (p & 7) * 192 + (p >> 3);
    const int w = L / 24, r_ = L - w * 24;
    const int b = (r_ / 6) * 64 + w;
    const int h = r_ - (r_ / 6) * 6;
    const f32x4 zero4 = {0.f, 0.f, 0.f, 0.f};

    // stage K (this head's 32 channels) into A-frag layout [key][40]
    for (int i = tid; i < 1408; i += 512) {
        int key = i >> 2, part = i & 3;
        *(short8*)(Ks + key * 40 + part * 8) =
            *(const short8*)(Kb + ((size_t)b * NPAD + key) * CEMB + h * 32 + part * 8);
    }
    // stage V^T (contiguous copy of this (b,h) plane)
    const unsigned short* vsrc = Vtb + (size_t)(b * NH + h) * 32 * 360;
    for (int i = tid; i < 1440; i += 512) {
        *(short8*)(Vt + i * 8) = *(const short8*)(vsrc + i * 8);
    }
    // per-wave Q B-frags straight from global
    short8 qa[3] = {};
#pragma unroll
    for (int i = 0; i < 3; i++) {
        int mt = wave + (i << 3);
        if (mt < 22)
            qa[i] = *(const short8*)(Qb + ((size_t)b * NPAD + mt * 16 + l16) * CEMB + h * 32 + q8);
    }
    __syncthreads();

    const unsigned short* bF = biasF + (size_t)h * FPLANE;
    const unsigned short* mF = maskF + (size_t)w * FPLANE;
    const int lane4 = lane << 2;
#pragma unroll
    for (int i = 0; i < 3; i++) {
        int mt = wave + (i << 3);
        if (mt >= 22) continue;             // wave-uniform, no barriers below
        float rp = 0.f;
        f32x4 o0 = zero4, o1 = zero4;
        int off = mt * 5632;                // (mt*11 + ch)*512 + t*256, coalesced frag tables
        ushort4 bt0c = *(const ushort4*)(bF + off + lane4);
        ushort4 mk0c = *(const ushort4*)(mF + off + lane4);
        ushort4 bt1c = *(const ushort4*)(bF + off + 256 + lane4);
        ushort4 mk1c = *(const ushort4*)(mF + off + 256 + lane4);
        for (int ch = 0; ch < 11; ch++) {
            const int kb_ = ch * 32;
            const int offn = (ch < 10) ? off + 512 : off;   // last iter: harmless reload
            ushort4 bt0n = *(const ushort4*)(bF + offn + lane4);
            ushort4 mk0n = *(const ushort4*)(mF + offn + lane4);
            ushort4 bt1n = *(const ushort4*)(bF + offn + 256 + lane4);
            ushort4 mk1n = *(const ushort4*)(mF + offn + 256 + lane4);
            // C operands = bias + mask (off the dependent path; MFMA adds them free)
            f32x4 c0, c1;
            c0[0] = bf2f(bt0c.x) + bf2f(mk0c.x);
            c0[1] = bf2f(bt0c.y) + bf2f(mk0c.y);
            c0[2] = bf2f(bt0c.z) + bf2f(mk0c.z);
            c0[3] = bf2f(bt0c.w) + bf2f(mk0c.w);
            c1[0] = bf2f(bt1c.x) + bf2f(mk1c.x);
            c1[1] = bf2f(bt1c.y) + bf2f(mk1c.y);
            c1[2] = bf2f(bt1c.z) + bf2f(mk1c.z);
            c1[3] = bf2f(bt1c.w) + bf2f(mk1c.w);
            const short8 k0f = *(const short8*)(Ks + (kb_ + l16) * 40 + q8);
            const short8 k1f = *(const short8*)(Ks + (kb_ + 16 + l16) * 40 + q8);
            // S^T tiles: lane holds S[q=l16][key = kb_ + 16t + q4 + r] in s{t}[r]
            f32x4 s0 = __builtin_amdgcn_mfma_f32_16x16x32_bf16(k0f, qa[i], c0, 0, 0, 0);
            f32x4 s1 = __builtin_amdgcn_mfma_f32_16x16x32_bf16(k1f, qa[i], c1, 0, 0, 0);
            float p00 = __builtin_amdgcn_exp2f(s0[0]);
            float p01 = __builtin_amdgcn_exp2f(s0[1]);
            float p02 = __builtin_amdgcn_exp2f(s0[2]);
            float p03 = __builtin_amdgcn_exp2f(s0[3]);
            float p10 = __builtin_amdgcn_exp2f(s1[0]);
            float p11 = __builtin_amdgcn_exp2f(s1[1]);
            float p12 = __builtin_amdgcn_exp2f(s1[2]);
            float p13 = __builtin_amdgcn_exp2f(s1[3]);
            rp += ((p00 + p01) + (p02 + p03)) + ((p10 + p11) + (p12 + p13));
            // pack to bf16 pairs: c0=keys(q4,q4+1) c1=(q4+2,q4+3) [t=0]; c2,c3 same [t=1]
            unsigned int e0 = cvt_pk_bf16(p00, p01);
            unsigned int e1 = cvt_pk_bf16(p02, p03);
            unsigned int e2 = cvt_pk_bf16(p10, p11);
            unsigned int e3 = cvt_pk_bf16(p12, p13);
            // 4x4 u32 cross-quad transpose via permlane swaps (VALU only)
            uint2v sa = __builtin_amdgcn_permlane32_swap(e0, e2, false, false);
            uint2v sb = __builtin_amdgcn_permlane32_swap(e1, e3, false, false);
            uint2v ta = __builtin_amdgcn_permlane16_swap(sa[0], sa[1], false, false);
            uint2v tb = __builtin_amdgcn_permlane16_swap(sb[0], sb[1], false, false);
            // PV A-frag: A[q=l16][key kb_ + q8 + j], j=0..7
            const short8 pa = __builtin_bit_cast(short8, (uint4v){ta[0], tb[0], ta[1], tb[1]});
            const short8 v0 = *(const short8*)(Vt + l16 * 360 + kb_ + q8);
            const short8 v1 = *(const short8*)(Vt + (16 + l16) * 360 + kb_ + q8);
            o0 = __builtin_amdgcn_mfma_f32_16x16x32_bf16(pa, v0, o0, 0, 0, 0);
            o1 = __builtin_amdgcn_mfma_f32_16x16x32_bf16(pa, v1, o1, 0, 0, 0);
            bt0c = bt0n; mk0c = mk0n; bt1c = bt1n; mk1c = mk1n;
            off = offn;
        }
        // rp holds this quad's partial key-sum for q=l16; reduce across quads
        rp += __shfl_xor(rp, 16);
        rp += __shfl_xor(rp, 32);
        float inv = 1.f / rp;               // inverse row-sum for q = mt*16 + l16
#pragma unroll
        for (int r = 0; r < 4; r++) {
            // output row n = mt*16 + q4 + r: fetch its inv from lane l16 = q4+r
            float invr = __shfl(inv, (lane & 48) | (q4 + r));
            int n = mt * 16 + q4 + r;
            if (n < NTOK) {
                size_t base = ((size_t)b * NTOK + n) * CEMB + h * 32;
                attnb[base + l16] = f2bf(o0[r] * invr);
                attnb[base + 16 + l16] = f2bf(o1[r] * invr);
            }
        }
    }
}

// ---------------- output projection: out = attn @ proj_w^T + proj_b ----------------
// Weights staged in LDS ([192][200], 76.8 KB); 8 M-tiles per block (1/wave).
__global__ __launch_bounds__(512, 2)
void proj_kernel(const unsigned short* __restrict__ attnb, const unsigned short* __restrict__ pwb,
                 const float* __restrict__ proj_b, float* __restrict__ out) {
    extern __shared__ char smem[];
    unsigned short* Ws = (unsigned short*)smem;   // [192][200] padded
    const int tid = threadIdx.x;
    const int wave = tid >> 6, lane = tid & 63;
    const int quad = lane >> 4, l16 = lane & 15;
    for (int i = tid; i < 4608; i += 512) {
        int r = i / 24, c8 = i - r * 24;
        *(short8*)(Ws + r * 200 + c8 * 8) = *(const short8*)(pwb + (size_t)r * CEMB + c8 * 8);
    }
    float pb[12];
#pragma unroll
    for (int nt = 0; nt < 12; nt++) pb[nt] = proj_b[nt * 16 + l16];
    __syncthreads();

    const int mt = blockIdx.x * 8 + wave;   // 686*8 = 5488 exact
    const f32x4 zero4 = {0.f, 0.f, 0.f, 0.f};
    f32x4 acc[12];
#pragma unroll
    for (int nt = 0; nt < 12; nt++) acc[nt] = zero4;
#pragma unroll
    for (int ks = 0; ks < 6; ks++) {
        const short8 a = *(const short8*)(attnb + ((size_t)mt * 16 + l16) * CEMB + ks * 32 + (quad << 3));
#pragma unroll
        for (int nt = 0; nt < 12; nt++) {
            const short8 bfrag = *(const short8*)(Ws + (nt * 16 + l16) * 200 + ks * 32 + (quad << 3));
            acc[nt] = __builtin_amdgcn_mfma_f32_16x16x32_bf16(a, bfrag, acc[nt], 0, 0, 0);
        }
    }
#pragma unroll
    for (int nt = 0; nt < 12; nt++) {
#pragma unroll
        for (int r = 0; r < 4; r++) {
            int m = mt * 16 + (quad << 2) + r;
            out[(size_t)m * CEMB + nt * 16 + l16] = acc[nt][r] + pb[nt];
        }
    }
}

// ---------------- launch ----------------
extern "C" void kernel_launch(void* const* d_in, const int* in_sizes, int n_in,
                              void* d_out, int out_size, void* d_ws, size_t ws_size,
                              hipStream_t stream) {
    (void)in_sizes; (void)n_in; (void)out_size; (void)ws_size;
    const float* x_in    = (const float*)d_in[0];
    const float* x_cross = (const float*)d_in[1];
    const float* mask    = (const float*)d_in[2];
    const float* q_w     = (const float*)d_in[3];
    const float* kv_w    = (const float*)d_in[4];
    const float* proj_w  = (const float*)d_in[5];
    const float* proj_b  = (const float*)d_in[6];
    const float* btab    = (const float*)d_in[7];
    const int*   rel     = (const int*)d_in[8];
    float* out = (float*)d_out;
    char* ws = (char*)d_ws;

    // ws layout (bytes), total 155,955,200:
    unsigned short* qwb   = (unsigned short*)(ws + 0);           //     73,728
    unsigned short* kvwb  = (unsigned short*)(ws + 73728);       //    147,456
    unsigned short* pwb   = (unsigned short*)(ws + 221184);      //     73,728
    unsigned short* biasF = (unsigned short*)(ws + 294912);      //  1,486,848
    unsigned short* maskF = (unsigned short*)(ws + 1781760);     // 15,859,712
    unsigned short* attnb = (unsigned short*)(ws + 17641472);    // 33,718,272
    unsigned short* Qb    = (unsigned short*)(ws + 51359744);    // 34,603,008
    unsigned short* Kb    = (unsigned short*)(ws + 85962752);    // 34,603,008
    unsigned short* Vtb   = (unsigned short*)(ws + 120565760);   // 35,389,440

    prep_weights<<<576, 256, 0, stream>>>(q_w, kv_w, proj_w, qwb, kvwb, pwb);
    prep_biasF<<<728, 256, 0, stream>>>(btab, rel, biasF);
    prep_maskF<<<7744, 256, 0, stream>>>(mask, maskF);
    qkv_q_kernel<<<NB, 512, 76800, stream>>>(x_in, qwb, Qb);
    qkv_kv_kernel<<<NB, 512, 76800, stream>>>(x_cross, kvwb, Kb, Vtb);
    attn_kernel<<<NB * NH, 512, 51200, stream>>>(Qb, Kb, Vtb, biasF, maskF, attnb);
    proj_kernel<<<686, 512, 76800, stream>>>(attnb, pwb, proj_b, out);
}